// Round 4
// baseline (249.066 us; speedup 1.0000x reference)
//
#include <hip/hip_runtime.h>
#include <math.h>

// Problem constants (B=1, LAYERS=33, HEADS=20, SEQ=512)
#define SEQ   512
#define NF    660
#define CROP  510
#define EOSI  2
#define RT    16           // rows per block (pass1)
#define NT_   32           // row tiles
#define NG    32           // head groups (exact-grid: 20 groups of 21 + 12 of 20)

typedef float f4 __attribute__((ext_vector_type(4)));

__device__ __forceinline__ f4 ntl4(const float* p) {
    return __builtin_nontemporal_load((const f4*)p);
}

// load one row-pair (2 rows x 2 float4) of head f starting at absolute row prow
#define LOADP(buf, f, prow) do {                                              \
    const float* _b = A + ((size_t)(f) << 18) + ((size_t)(prow) << 9);        \
    buf[0] = ntl4(_b + 4 * lane);                                             \
    buf[1] = ntl4(_b + 256 + 4 * lane);                                       \
    buf[2] = ntl4(_b + 512 + 4 * lane);                                       \
    buf[3] = ntl4(_b + 768 + 4 * lane);                                       \
} while (0)

// consume one row-pair: wa += wf*v, cacc += mi*v, rowsum (POFF is 0 or 1, literal)
#define COMP(buf, wf, cacc, wa, POFF, f) do {                                 \
    _Pragma("unroll")                                                         \
    for (int rr = 0; rr < 2; ++rr) {                                          \
        const float mi = mrow[(POFF) * 2 + rr];                               \
        f4 x0 = buf[2 * rr], x1 = buf[2 * rr + 1];                            \
        float vals[8] = {x0[0], x0[1], x0[2], x0[3],                          \
                         x1[0], x1[1], x1[2], x1[3]};                         \
        float rs = 0.f;                                                       \
        _Pragma("unroll")                                                     \
        for (int e = 0; e < 8; ++e) {                                         \
            const float v = vals[e];                                          \
            wa[rr][e] += (wf) * v;                                            \
            rs += mskv[e] * v;                                                \
            cacc[e] += mi * v;                                                \
        }                                                                     \
        _Pragma("unroll")                                                     \
        for (int off = 32; off > 0; off >>= 1)                                \
            rs += __shfl_down(rs, off, 64);                                   \
        if (lane == 0)                                                        \
            rowsum[((size_t)(f) << 9) + row0 + (POFF) * 2 + rr] = rs;         \
    }                                                                         \
} while (0)

// ---------------- Pass 1: stream 692MB once, register-pipelined, exact 1024 grid
__global__ __launch_bounds__(256, 4) void pass1_kernel(
    const float* __restrict__ A, const int* __restrict__ tokens,
    const float* __restrict__ weight,
    float* __restrict__ WApart, float* __restrict__ rowsum, float* __restrict__ colpart)
{
    __shared__ float msk[SEQ];
    __shared__ float col_lds[2][4][2][SEQ];   // [pingpong][wave][head-in-pair][col]

    const int t = blockIdx.x, g = blockIdx.y;
    const int tid = threadIdx.x, wave = tid >> 6, lane = tid & 63;

    // group -> head range: groups 0..19 have 21 heads, 20..31 have 20 heads
    const int f0   = (g < 20) ? 21 * g : 420 + 20 * (g - 20);
    const int tail = (g < 20) ? 1 : 0;        // pairs = 10 uniformly

    for (int j = tid; j < SEQ; j += 256)
        msk[j] = (j >= 1 && j <= SEQ - 2 && tokens[j] != EOSI) ? 1.f : 0.f;
    __syncthreads();

    float mskv[8];
    #pragma unroll
    for (int e = 0; e < 8; ++e)
        mskv[e] = msk[(e >> 2) * 256 + 4 * lane + (e & 3)];

    const int row0 = t * RT + wave * 4;
    const float mrow[4] = {msk[row0], msk[row0 + 1], msk[row0 + 2], msk[row0 + 3]};

    float waLo[2][8], waHi[2][8];
    #pragma unroll
    for (int r = 0; r < 2; ++r)
        #pragma unroll
        for (int e = 0; e < 8; ++e) { waLo[r][e] = 0.f; waHi[r][e] = 0.f; }

    f4 bufA[4], bufB[4];
    LOADP(bufA, f0, row0);                    // prime

    for (int hp = 0; hp < 10; ++hp) {
        const int fa = f0 + 2 * hp, fb = fa + 1;
        const float wf0 = weight[fa], wf1 = weight[fb];
        float caccA[8] = {0, 0, 0, 0, 0, 0, 0, 0};
        float caccB[8] = {0, 0, 0, 0, 0, 0, 0, 0};

        LOADP(bufB, fa, row0 + 2);
        COMP(bufA, wf0, caccA, waLo, 0, fa);
        LOADP(bufA, fb, row0);
        COMP(bufB, wf0, caccA, waHi, 1, fa);
        LOADP(bufB, fb, row0 + 2);
        COMP(bufA, wf1, caccB, waLo, 0, fb);
        if (hp < 9)       LOADP(bufA, fa + 2, row0);     // next pair's head0
        else if (tail)    LOADP(bufA, f0 + 20, row0);    // tail head
        COMP(bufB, wf1, caccB, waHi, 1, fb);

        const int pp = hp & 1;
        #pragma unroll
        for (int e = 0; e < 8; ++e) {
            const int c = (e >> 2) * 256 + 4 * lane + (e & 3);
            col_lds[pp][wave][0][c] = caccA[e];
            col_lds[pp][wave][1][c] = caccB[e];
        }
        __syncthreads();
        #pragma unroll
        for (int jj = 0; jj < 4; ++jj) {
            const int j = jj * 256 + tid;
            const int h = j >> 9, c = j & 511;
            colpart[((size_t)t * NF + fa + h) * SEQ + c] =
                col_lds[pp][0][h][c] + col_lds[pp][1][h][c]
              + col_lds[pp][2][h][c] + col_lds[pp][3][h][c];
        }
    }

    if (tail) {
        const int ft = f0 + 20;
        const float wft = weight[ft];
        float caccA[8] = {0, 0, 0, 0, 0, 0, 0, 0};
        LOADP(bufB, ft, row0 + 2);
        COMP(bufA, wft, caccA, waLo, 0, ft);
        COMP(bufB, wft, caccA, waHi, 1, ft);
        #pragma unroll
        for (int e = 0; e < 8; ++e)
            col_lds[0][wave][0][(e >> 2) * 256 + 4 * lane + (e & 3)] = caccA[e];
        __syncthreads();
        #pragma unroll
        for (int jj = 0; jj < 2; ++jj) {
            const int c = jj * 256 + tid;
            colpart[((size_t)t * NF + ft) * SEQ + c] =
                col_lds[0][0][0][c] + col_lds[0][1][0][c]
              + col_lds[0][2][0][c] + col_lds[0][3][0][c];
        }
    }

    // flush WApart (write-once, float4 coalesced)
    float* __restrict__ wp = WApart + (size_t)g * SEQ * SEQ;
    #pragma unroll
    for (int rr = 0; rr < 2; ++rr) {
        f4 l0 = {waLo[rr][0], waLo[rr][1], waLo[rr][2], waLo[rr][3]};
        f4 l1 = {waLo[rr][4], waLo[rr][5], waLo[rr][6], waLo[rr][7]};
        *(f4*)(wp + ((size_t)(row0 + rr) << 9) + 4 * lane) = l0;
        *(f4*)(wp + ((size_t)(row0 + rr) << 9) + 256 + 4 * lane) = l1;
        f4 h0 = {waHi[rr][0], waHi[rr][1], waHi[rr][2], waHi[rr][3]};
        f4 h1 = {waHi[rr][4], waHi[rr][5], waHi[rr][6], waHi[rr][7]};
        *(f4*)(wp + ((size_t)(row0 + 2 + rr) << 9) + 4 * lane) = h0;
        *(f4*)(wp + ((size_t)(row0 + 2 + rr) << 9) + 256 + 4 * lane) = h1;
    }
}

// ---------------- Kernel 2 (merged): WA-reduce + per-head a1/a12/scale --------
__global__ __launch_bounds__(512) void kernel2(
    const float* __restrict__ WApart, float* __restrict__ WA,
    const float* __restrict__ rowsum, const float* __restrict__ colpart,
    const int* __restrict__ tokens, const float* __restrict__ weight,
    float* __restrict__ a1, float* __restrict__ sfac)
{
    __shared__ float part[8];
    const int b = blockIdx.x, tid = threadIdx.x;
    if (b < 128) {
        const size_t idx4 = (size_t)b * 512 + tid;     // float4 index, 65536 total
        f4 a = ntl4(WApart + 4 * idx4);
        #pragma unroll
        for (int g = 1; g < NG; ++g) {
            f4 x = ntl4(WApart + (size_t)g * (SEQ * SEQ) + 4 * idx4);
            a += x;
        }
        *(f4*)(WA + 4 * idx4) = a;
    } else {
        const int f = b - 128, j = tid;
        float cs = 0.f;
        #pragma unroll
        for (int t = 0; t < NT_; ++t)
            cs += colpart[((size_t)t * NF + f) * SEQ + j];
        const float m = (j >= 1 && j <= SEQ - 2 && tokens[j] != EOSI) ? 1.f : 0.f;
        const float v = m * (rowsum[((size_t)f << 9) + j] + cs);
        a1[((size_t)f << 9) + j] = v;
        float s = v;
        #pragma unroll
        for (int off = 32; off > 0; off >>= 1)
            s += __shfl_down(s, off, 64);
        const int wave = tid >> 6, lane = tid & 63;
        if (lane == 0) part[wave] = s;
        __syncthreads();
        if (tid == 0) {
            float a12 = 0.f;
            #pragma unroll
            for (int k = 0; k < 8; ++k) a12 += part[k];
            sfac[f] = weight[f] / a12;
        }
    }
}

// ---------------- Pass 3: rank-660 outer-product + WA + sigmoid ----------------
// grid (32,32) = 1024 blocks; 16x16 output tile, 1 output/thread; 32-f chunks
__global__ __launch_bounds__(256) void pass3_kernel(
    const float* __restrict__ WA, const float* __restrict__ a1,
    const float* __restrict__ sfac, const int* __restrict__ tokens,
    const float* __restrict__ bias, float* __restrict__ out)
{
    const int TI = blockIdx.y * 16;
    const int TJ = blockIdx.x * 16;
    const int tid = threadIdx.x;
    const int tx = tid & 15, ty = tid >> 4;

    __shared__ float u_s[32][17];
    __shared__ float v_s[32][17];

    float acc = 0.f;

    for (int f0 = 0; f0 < NF; f0 += 32) {
        #pragma unroll
        for (int c = 0; c < 4; ++c) {
            const int e = c * 256 + tid;        // 0..1023
            const int arr = e >> 9, ff = (e >> 4) & 31, ii = e & 15;
            const int f = f0 + ff;
            float val = 0.f;
            if (f < NF) {
                if (arr == 0) {
                    int Iu = TI + 1 + ii; if (Iu > SEQ - 1) Iu = SEQ - 1;
                    val = a1[((size_t)f << 9) + Iu] * sfac[f];
                } else {
                    int Ju = TJ + 1 + ii; if (Ju > SEQ - 1) Ju = SEQ - 1;
                    val = a1[((size_t)f << 9) + Ju];
                }
            }
            if (arr == 0) u_s[ff][ii] = val; else v_s[ff][ii] = val;
        }
        __syncthreads();
        #pragma unroll
        for (int ff = 0; ff < 32; ++ff)
            acc += u_s[ff][ty] * v_s[ff][tx];
        __syncthreads();
    }

    const int i = TI + ty, j = TJ + tx;
    if (i < CROP && j < CROP) {
        const int I = i + 1, J = j + 1;
        const float mi = (tokens[I] != EOSI) ? 1.f : 0.f;
        const float mj = (tokens[J] != EOSI) ? 1.f : 0.f;
        const float first = mi * mj * (WA[((size_t)I << 9) + J] + WA[((size_t)J << 9) + I]);
        const float logit = first - acc + bias[0];
        out[(size_t)i * CROP + j] = 1.f / (1.f + expf(-logit));
    }
}

extern "C" void kernel_launch(void* const* d_in, const int* in_sizes, int n_in,
                              void* d_out, int out_size, void* d_ws, size_t ws_size,
                              hipStream_t stream) {
    const int*   tokens = (const int*)d_in[0];
    const float* A      = (const float*)d_in[1];
    const float* weight = (const float*)d_in[2];
    const float* bias   = (const float*)d_in[3];
    float* out = (float*)d_out;

    // workspace (floats), all write-once, no zeroing:
    // WApart[32*512*512] | colpart[32*660*512] | WA[512*512] | rowsum[660*512] | a1[660*512] | sfac[660]
    float* WApart  = (float*)d_ws;
    float* colpart = WApart + (size_t)NG * SEQ * SEQ;
    float* WA      = colpart + (size_t)NT_ * NF * SEQ;
    float* rowsum  = WA + (size_t)SEQ * SEQ;
    float* a1      = rowsum + (size_t)NF * SEQ;
    float* sfac    = a1 + (size_t)NF * SEQ;

    dim3 g1(NT_, NG);   // 32 x 32 = 1024 blocks, exact 4/CU
    pass1_kernel<<<g1, 256, 0, stream>>>(A, tokens, weight, WApart, rowsum, colpart);

    kernel2<<<128 + NF, 512, 0, stream>>>(WApart, WA, rowsum, colpart, tokens, weight, a1, sfac);

    dim3 g3(32, 32);
    pass3_kernel<<<g3, 256, 0, stream>>>(WA, a1, sfac, tokens, bias, out);
}

// Round 5
// 220.582 us; speedup vs baseline: 1.1291x; 1.1291x over previous
//
#include <hip/hip_runtime.h>
#include <math.h>

// Problem constants (B=1, LAYERS=33, HEADS=20, SEQ=512)
#define SEQ   512
#define NF    660
#define CROP  510
#define EOSI  2
#define RT    16           // rows per block (pass1)
#define GH    20           // heads per group (pass1)
#define NT_   32           // row tiles
#define NG    33           // head groups

typedef float f4 __attribute__((ext_vector_type(4)));
typedef float f2 __attribute__((ext_vector_type(2)));

// barrier that waits only LDS ops -- keeps global-load prefetch in flight
// (cross-wave data flows only through LDS; global loads land in private regs)
#define BARRIER_LGKM() asm volatile("s_waitcnt lgkmcnt(0)\n\ts_barrier" ::: "memory")

// load one row-pair (2 rows x 2 float4) of head f starting at absolute row prow
#define LOADP(buf, f, prow) do {                                              \
    const float* _b = A + ((size_t)(f) << 18) + ((size_t)(prow) << 9);        \
    buf[0] = *(const f4*)(_b + 4 * lane);                                     \
    buf[1] = *(const f4*)(_b + 256 + 4 * lane);                               \
    buf[2] = *(const f4*)(_b + 512 + 4 * lane);                               \
    buf[3] = *(const f4*)(_b + 768 + 4 * lane);                               \
} while (0)

// consume one row-pair: wa += wf*v, cacc += mi*v, rowsum (POFF is 0 or 1, literal)
#define COMP(buf, wf, cacc, wa, POFF, f) do {                                 \
    _Pragma("unroll")                                                         \
    for (int rr = 0; rr < 2; ++rr) {                                          \
        const float mi = mrow[(POFF) * 2 + rr];                               \
        f4 x0 = buf[2 * rr], x1 = buf[2 * rr + 1];                            \
        float vals[8] = {x0[0], x0[1], x0[2], x0[3],                          \
                         x1[0], x1[1], x1[2], x1[3]};                         \
        float rs = 0.f;                                                       \
        _Pragma("unroll")                                                     \
        for (int e = 0; e < 8; ++e) {                                         \
            const float v = vals[e];                                          \
            wa[rr][e] += (wf) * v;                                            \
            rs += mskv[e] * v;                                                \
            cacc[e] += mi * v;                                                \
        }                                                                     \
        _Pragma("unroll")                                                     \
        for (int off = 32; off > 0; off >>= 1)                                \
            rs += __shfl_down(rs, off, 64);                                   \
        if (lane == 0)                                                        \
            rowsum[((size_t)(f) << 9) + row0 + (POFF) * 2 + rr] = rs;         \
    }                                                                         \
} while (0)

// ---------------- Pass 1: stream 692MB once, register-pipelined ----------------
// grid (32 row-tiles, 33 head-groups), block 256 (4 waves). No min-wave bound
// (R4 post-mortem: forcing VGPR<=128 spilled). Barriers are lgkm-only so the
// prefetch stream stays live across the per-head-pair col-combines.
__global__ __launch_bounds__(256) void pass1_kernel(
    const float* __restrict__ A, const int* __restrict__ tokens,
    const float* __restrict__ weight,
    float* __restrict__ WApart, float* __restrict__ rowsum, float* __restrict__ colpart)
{
    __shared__ float msk[SEQ];
    __shared__ float col_lds[2][4][2][SEQ];   // [pingpong][wave][head-in-pair][col]

    const int t = blockIdx.x, g = blockIdx.y;
    const int tid = threadIdx.x, wave = tid >> 6, lane = tid & 63;

    for (int j = tid; j < SEQ; j += 256)
        msk[j] = (j >= 1 && j <= SEQ - 2 && tokens[j] != EOSI) ? 1.f : 0.f;
    BARRIER_LGKM();

    float mskv[8];
    #pragma unroll
    for (int e = 0; e < 8; ++e)
        mskv[e] = msk[(e >> 2) * 256 + 4 * lane + (e & 3)];

    const int row0 = t * RT + wave * 4;
    const float mrow[4] = {msk[row0], msk[row0 + 1], msk[row0 + 2], msk[row0 + 3]};

    float waLo[2][8], waHi[2][8];
    #pragma unroll
    for (int r = 0; r < 2; ++r)
        #pragma unroll
        for (int e = 0; e < 8; ++e) { waLo[r][e] = 0.f; waHi[r][e] = 0.f; }

    f4 bufA[4], bufB[4];
    const int fbase = g * GH;
    LOADP(bufA, fbase, row0);               // prime the pipeline

    for (int hp = 0; hp < 10; ++hp) {
        const int fa = fbase + 2 * hp, fb = fa + 1;
        const float wf0 = weight[fa], wf1 = weight[fb];
        float caccA[8] = {0, 0, 0, 0, 0, 0, 0, 0};
        float caccB[8] = {0, 0, 0, 0, 0, 0, 0, 0};

        LOADP(bufB, fa, row0 + 2);
        COMP(bufA, wf0, caccA, waLo, 0, fa);
        LOADP(bufA, fb, row0);
        COMP(bufB, wf0, caccA, waHi, 1, fa);
        LOADP(bufB, fb, row0 + 2);
        COMP(bufA, wf1, caccB, waLo, 0, fb);
        if (hp < 9) LOADP(bufA, fa + 2, row0);   // next head-pair (pair0)
        COMP(bufB, wf1, caccB, waHi, 1, fb);

        // cross-wave col-sum combine for heads fa,fb (ping-pong, lgkm-only barrier)
        const int pp = hp & 1;
        #pragma unroll
        for (int e = 0; e < 8; ++e) {
            const int c = (e >> 2) * 256 + 4 * lane + (e & 3);
            col_lds[pp][wave][0][c] = caccA[e];
            col_lds[pp][wave][1][c] = caccB[e];
        }
        BARRIER_LGKM();
        #pragma unroll
        for (int h = 0; h < 2; ++h) {
            const int c = 2 * tid;               // cols c, c+1 of head h
            f2 s;
            s[0] = col_lds[pp][0][h][c]     + col_lds[pp][1][h][c]
                 + col_lds[pp][2][h][c]     + col_lds[pp][3][h][c];
            s[1] = col_lds[pp][0][h][c + 1] + col_lds[pp][1][h][c + 1]
                 + col_lds[pp][2][h][c + 1] + col_lds[pp][3][h][c + 1];
            *(f2*)(colpart + ((size_t)t * NF + fa + h) * SEQ + c) = s;
        }
    }

    // flush WApart (write-once, float4 coalesced)
    float* __restrict__ wp = WApart + (size_t)g * SEQ * SEQ;
    #pragma unroll
    for (int rr = 0; rr < 2; ++rr) {
        f4 l0 = {waLo[rr][0], waLo[rr][1], waLo[rr][2], waLo[rr][3]};
        f4 l1 = {waLo[rr][4], waLo[rr][5], waLo[rr][6], waLo[rr][7]};
        *(f4*)(wp + ((size_t)(row0 + rr) << 9) + 4 * lane) = l0;
        *(f4*)(wp + ((size_t)(row0 + rr) << 9) + 256 + 4 * lane) = l1;
        f4 h0 = {waHi[rr][0], waHi[rr][1], waHi[rr][2], waHi[rr][3]};
        f4 h1 = {waHi[rr][4], waHi[rr][5], waHi[rr][6], waHi[rr][7]};
        *(f4*)(wp + ((size_t)(row0 + 2 + rr) << 9) + 4 * lane) = h0;
        *(f4*)(wp + ((size_t)(row0 + 2 + rr) << 9) + 256 + 4 * lane) = h1;
    }
}

// ---------------- Kernel 2 (merged): WA-reduce + per-head a1/a12/scale --------
// grid 128+660 blocks x 512 threads. Blocks [0,128): WA = sum_g WApart[g].
// Blocks [128,788): head f = b-128: a1, a12, sfac.
__global__ __launch_bounds__(512) void kernel2(
    const float* __restrict__ WApart, float* __restrict__ WA,
    const float* __restrict__ rowsum, const float* __restrict__ colpart,
    const int* __restrict__ tokens, const float* __restrict__ weight,
    float* __restrict__ a1, float* __restrict__ sfac)
{
    __shared__ float part[8];
    const int b = blockIdx.x, tid = threadIdx.x;
    if (b < 128) {
        const size_t idx4 = (size_t)b * 512 + tid;     // float4 index, 65536 total
        f4 a = *(const f4*)(WApart + 4 * idx4);
        #pragma unroll 8
        for (int g = 1; g < NG; ++g) {
            f4 x = *(const f4*)(WApart + (size_t)g * (SEQ * SEQ) + 4 * idx4);
            a += x;
        }
        *(f4*)(WA + 4 * idx4) = a;
    } else {
        const int f = b - 128, j = tid;
        float cs = 0.f;
        #pragma unroll 8
        for (int t = 0; t < NT_; ++t)
            cs += colpart[((size_t)t * NF + f) * SEQ + j];
        const float m = (j >= 1 && j <= SEQ - 2 && tokens[j] != EOSI) ? 1.f : 0.f;
        const float v = m * (rowsum[((size_t)f << 9) + j] + cs);
        a1[((size_t)f << 9) + j] = v;
        float s = v;
        #pragma unroll
        for (int off = 32; off > 0; off >>= 1)
            s += __shfl_down(s, off, 64);
        const int wave = tid >> 6, lane = tid & 63;
        if (lane == 0) part[wave] = s;
        __syncthreads();
        if (tid == 0) {
            float a12 = 0.f;
            #pragma unroll
            for (int k = 0; k < 8; ++k) a12 += part[k];
            sfac[f] = weight[f] / a12;
        }
    }
}

// ---------------- Pass 3: rank-660 outer-product + WA + sigmoid ----------------
// grid (32,32) = 1024 blocks; 16x16 output tile, 1 output/thread; 32-f chunks
__global__ __launch_bounds__(256) void pass3_kernel(
    const float* __restrict__ WA, const float* __restrict__ a1,
    const float* __restrict__ sfac, const int* __restrict__ tokens,
    const float* __restrict__ bias, float* __restrict__ out)
{
    const int TI = blockIdx.y * 16;
    const int TJ = blockIdx.x * 16;
    const int tid = threadIdx.x;
    const int tx = tid & 15, ty = tid >> 4;

    __shared__ float u_s[32][17];
    __shared__ float v_s[32][17];

    float acc = 0.f;

    for (int f0 = 0; f0 < NF; f0 += 32) {
        #pragma unroll
        for (int c = 0; c < 4; ++c) {
            const int e = c * 256 + tid;        // 0..1023
            const int arr = e >> 9, ff = (e >> 4) & 31, ii = e & 15;
            const int f = f0 + ff;
            float val = 0.f;
            if (f < NF) {
                if (arr == 0) {
                    int Iu = TI + 1 + ii; if (Iu > SEQ - 1) Iu = SEQ - 1;
                    val = a1[((size_t)f << 9) + Iu] * sfac[f];
                } else {
                    int Ju = TJ + 1 + ii; if (Ju > SEQ - 1) Ju = SEQ - 1;
                    val = a1[((size_t)f << 9) + Ju];
                }
            }
            if (arr == 0) u_s[ff][ii] = val; else v_s[ff][ii] = val;
        }
        __syncthreads();
        #pragma unroll
        for (int ff = 0; ff < 32; ++ff)
            acc += u_s[ff][ty] * v_s[ff][tx];
        __syncthreads();
    }

    const int i = TI + ty, j = TJ + tx;
    if (i < CROP && j < CROP) {
        const int I = i + 1, J = j + 1;
        const float mi = (tokens[I] != EOSI) ? 1.f : 0.f;
        const float mj = (tokens[J] != EOSI) ? 1.f : 0.f;
        const float first = mi * mj * (WA[((size_t)I << 9) + J] + WA[((size_t)J << 9) + I]);
        const float logit = first - acc + bias[0];
        out[(size_t)i * CROP + j] = 1.f / (1.f + expf(-logit));
    }
}

extern "C" void kernel_launch(void* const* d_in, const int* in_sizes, int n_in,
                              void* d_out, int out_size, void* d_ws, size_t ws_size,
                              hipStream_t stream) {
    const int*   tokens = (const int*)d_in[0];
    const float* A      = (const float*)d_in[1];
    const float* weight = (const float*)d_in[2];
    const float* bias   = (const float*)d_in[3];
    float* out = (float*)d_out;

    // workspace (floats), all write-once, no zeroing:
    // WApart[33*512*512] | colpart[32*660*512] | WA[512*512] | rowsum[660*512] | a1[660*512] | sfac[660]
    float* WApart  = (float*)d_ws;
    float* colpart = WApart + (size_t)NG * SEQ * SEQ;
    float* WA      = colpart + (size_t)NT_ * NF * SEQ;
    float* rowsum  = WA + (size_t)SEQ * SEQ;
    float* a1      = rowsum + (size_t)NF * SEQ;
    float* sfac    = a1 + (size_t)NF * SEQ;

    dim3 g1(NT_, NG);   // 32 x 33
    pass1_kernel<<<g1, 256, 0, stream>>>(A, tokens, weight, WApart, rowsum, colpart);

    kernel2<<<128 + NF, 512, 0, stream>>>(WApart, WA, rowsum, colpart, tokens, weight, a1, sfac);

    dim3 g3(32, 32);
    pass3_kernel<<<g3, 256, 0, stream>>>(WA, a1, sfac, tokens, bias, out);
}

// Round 6
// 215.664 us; speedup vs baseline: 1.1549x; 1.0228x over previous
//
#include <hip/hip_runtime.h>
#include <math.h>

// Problem constants (B=1, LAYERS=33, HEADS=20, SEQ=512)
#define SEQ   512
#define NF    660
#define CROP  510
#define EOSI  2
#define RT    16           // rows per block (pass1)
#define GH    20           // heads per group (pass1)
#define NT_   32           // row tiles
#define NG    33           // head groups

typedef float f4 __attribute__((ext_vector_type(4)));
typedef float f2 __attribute__((ext_vector_type(2)));

// barrier that waits only LDS ops -- keeps global-load prefetch in flight
#define BARRIER_LGKM() asm volatile("s_waitcnt lgkmcnt(0)\n\ts_barrier" ::: "memory")

// load one row-pair (2 rows x 2 float4) of head f starting at absolute row prow
#define LOADP(buf, f, prow) do {                                              \
    const float* _b = A + ((size_t)(f) << 18) + ((size_t)(prow) << 9);        \
    buf[0] = *(const f4*)(_b + 4 * lane);                                     \
    buf[1] = *(const f4*)(_b + 256 + 4 * lane);                               \
    buf[2] = *(const f4*)(_b + 512 + 4 * lane);                               \
    buf[3] = *(const f4*)(_b + 768 + 4 * lane);                               \
} while (0)

// consume one row-pair; rowsum partial goes to LDS rowstage (NO global store)
#define COMP(buf, wf, cacc, wa, POFF, h) do {                                 \
    _Pragma("unroll")                                                         \
    for (int rr = 0; rr < 2; ++rr) {                                          \
        const float mi = mrow[(POFF) * 2 + rr];                               \
        f4 x0 = buf[2 * rr], x1 = buf[2 * rr + 1];                            \
        float vals[8] = {x0[0], x0[1], x0[2], x0[3],                          \
                         x1[0], x1[1], x1[2], x1[3]};                         \
        float rs = 0.f;                                                       \
        _Pragma("unroll")                                                     \
        for (int e = 0; e < 8; ++e) {                                         \
            const float v = vals[e];                                          \
            wa[rr][e] += (wf) * v;                                            \
            rs += mskv[e] * v;                                                \
            cacc[e] += mi * v;                                                \
        }                                                                     \
        _Pragma("unroll")                                                     \
        for (int off = 32; off > 0; off >>= 1)                                \
            rs += __shfl_down(rs, off, 64);                                   \
        if (lane == 0)                                                        \
            rowstage[h][wave * 4 + (POFF) * 2 + rr] = rs;                     \
    }                                                                         \
} while (0)

// ---------------- Pass 1: stream 692MB once; hot loop has ZERO global stores --
// grid (32 row-tiles, 33 head-groups), block 256 (4 waves).
// All outputs staged in LDS, flushed coalesced at block end.
__global__ __launch_bounds__(256) void pass1_kernel(
    const float* __restrict__ A, const int* __restrict__ tokens,
    const float* __restrict__ weight,
    float* __restrict__ WApart, float* __restrict__ rowsum, float* __restrict__ colpart)
{
    __shared__ float msk[SEQ];                // 2 KB
    __shared__ float col_lds[2][4][SEQ];      // 16 KB per-head ping-pong
    __shared__ float colstage[GH][SEQ];       // 40 KB staged col sums
    __shared__ float rowstage[GH][RT];        // 1.25 KB staged row sums

    const int t = blockIdx.x, g = blockIdx.y;
    const int tid = threadIdx.x, wave = tid >> 6, lane = tid & 63;

    for (int j = tid; j < SEQ; j += 256)
        msk[j] = (j >= 1 && j <= SEQ - 2 && tokens[j] != EOSI) ? 1.f : 0.f;
    BARRIER_LGKM();

    float mskv[8];
    #pragma unroll
    for (int e = 0; e < 8; ++e)
        mskv[e] = msk[(e >> 2) * 256 + 4 * lane + (e & 3)];

    const int row0 = t * RT + wave * 4;
    const float mrow[4] = {msk[row0], msk[row0 + 1], msk[row0 + 2], msk[row0 + 3]};

    float waLo[2][8], waHi[2][8];
    #pragma unroll
    for (int r = 0; r < 2; ++r)
        #pragma unroll
        for (int e = 0; e < 8; ++e) { waLo[r][e] = 0.f; waHi[r][e] = 0.f; }

    f4 bufA[4], bufB[4];
    const int fbase = g * GH;
    LOADP(bufA, fbase, row0);                 // prime the pipeline

    for (int h = 0; h < GH; ++h) {
        const int f = fbase + h;
        const float wf = weight[f];
        float cacc[8] = {0, 0, 0, 0, 0, 0, 0, 0};

        LOADP(bufB, f, row0 + 2);             // current head, pair1
        COMP(bufA, wf, cacc, waLo, 0, h);
        if (h < GH - 1) LOADP(bufA, f + 1, row0);   // next head, pair0
        COMP(bufB, wf, cacc, waHi, 1, h);

        // cross-wave col-sum combine -> colstage (LDS only, 1 lgkm barrier)
        const int pp = h & 1;
        #pragma unroll
        for (int e = 0; e < 8; ++e)
            col_lds[pp][wave][(e >> 2) * 256 + 4 * lane + (e & 3)] = cacc[e];
        BARRIER_LGKM();
        {
            const int c = 2 * tid;
            f2 s;
            s[0] = col_lds[pp][0][c]     + col_lds[pp][1][c]
                 + col_lds[pp][2][c]     + col_lds[pp][3][c];
            s[1] = col_lds[pp][0][c + 1] + col_lds[pp][1][c + 1]
                 + col_lds[pp][2][c + 1] + col_lds[pp][3][c + 1];
            *(f2*)&colstage[h][c] = s;
        }
    }

    BARRIER_LGKM();   // colstage/rowstage complete

    // ---- flush colstage -> colpart: 20 heads x 512 cols contiguous in global
    {
        float* __restrict__ dst = colpart + ((size_t)t * NF + fbase) * SEQ;
        const float* __restrict__ srcl = &colstage[0][0];
        #pragma unroll
        for (int it = 0; it < 10; ++it) {
            const int fl = (it * 256 + tid) * 4;
            *(f4*)(dst + fl) = *(const f4*)(srcl + fl);
        }
    }
    // ---- flush rowstage -> rowsum (16 consecutive floats per head)
    #pragma unroll
    for (int it = 0; it < 2; ++it) {
        const int e = it * 256 + tid;
        if (e < GH * RT) {
            const int h = e >> 4, r = e & 15;
            rowsum[((size_t)(fbase + h) << 9) + t * RT + r] = rowstage[h][r];
        }
    }
    // ---- flush WApart (write-once, float4 coalesced)
    float* __restrict__ wp = WApart + (size_t)g * SEQ * SEQ;
    #pragma unroll
    for (int rr = 0; rr < 2; ++rr) {
        f4 l0 = {waLo[rr][0], waLo[rr][1], waLo[rr][2], waLo[rr][3]};
        f4 l1 = {waLo[rr][4], waLo[rr][5], waLo[rr][6], waLo[rr][7]};
        *(f4*)(wp + ((size_t)(row0 + rr) << 9) + 4 * lane) = l0;
        *(f4*)(wp + ((size_t)(row0 + rr) << 9) + 256 + 4 * lane) = l1;
        f4 h0 = {waHi[rr][0], waHi[rr][1], waHi[rr][2], waHi[rr][3]};
        f4 h1 = {waHi[rr][4], waHi[rr][5], waHi[rr][6], waHi[rr][7]};
        *(f4*)(wp + ((size_t)(row0 + 2 + rr) << 9) + 4 * lane) = h0;
        *(f4*)(wp + ((size_t)(row0 + 2 + rr) << 9) + 256 + 4 * lane) = h1;
    }
}

// ---------------- Kernel 2 (merged): WA-reduce + per-head a1/a12/scale --------
__global__ __launch_bounds__(512) void kernel2(
    const float* __restrict__ WApart, float* __restrict__ WA,
    const float* __restrict__ rowsum, const float* __restrict__ colpart,
    const int* __restrict__ tokens, const float* __restrict__ weight,
    float* __restrict__ a1, float* __restrict__ sfac)
{
    __shared__ float part[8];
    const int b = blockIdx.x, tid = threadIdx.x;
    if (b < 128) {
        const size_t idx4 = (size_t)b * 512 + tid;     // float4 index, 65536 total
        f4 a = *(const f4*)(WApart + 4 * idx4);
        #pragma unroll 8
        for (int g = 1; g < NG; ++g) {
            f4 x = *(const f4*)(WApart + (size_t)g * (SEQ * SEQ) + 4 * idx4);
            a += x;
        }
        *(f4*)(WA + 4 * idx4) = a;
    } else {
        const int f = b - 128, j = tid;
        float cs = 0.f;
        #pragma unroll 8
        for (int t = 0; t < NT_; ++t)
            cs += colpart[((size_t)t * NF + f) * SEQ + j];
        const float m = (j >= 1 && j <= SEQ - 2 && tokens[j] != EOSI) ? 1.f : 0.f;
        const float v = m * (rowsum[((size_t)f << 9) + j] + cs);
        a1[((size_t)f << 9) + j] = v;
        float s = v;
        #pragma unroll
        for (int off = 32; off > 0; off >>= 1)
            s += __shfl_down(s, off, 64);
        const int wave = tid >> 6, lane = tid & 63;
        if (lane == 0) part[wave] = s;
        __syncthreads();
        if (tid == 0) {
            float a12 = 0.f;
            #pragma unroll
            for (int k = 0; k < 8; ++k) a12 += part[k];
            sfac[f] = weight[f] / a12;
        }
    }
}

// ---------------- Pass 3: rank-660 outer-product + WA + sigmoid ----------------
// grid (32,32) = 1024 blocks; 16x16 output tile, 1 output/thread; 32-f chunks
__global__ __launch_bounds__(256) void pass3_kernel(
    const float* __restrict__ WA, const float* __restrict__ a1,
    const float* __restrict__ sfac, const int* __restrict__ tokens,
    const float* __restrict__ bias, float* __restrict__ out)
{
    const int TI = blockIdx.y * 16;
    const int TJ = blockIdx.x * 16;
    const int tid = threadIdx.x;
    const int tx = tid & 15, ty = tid >> 4;

    __shared__ float u_s[32][17];
    __shared__ float v_s[32][17];

    float acc = 0.f;

    for (int f0 = 0; f0 < NF; f0 += 32) {
        #pragma unroll
        for (int c = 0; c < 4; ++c) {
            const int e = c * 256 + tid;        // 0..1023
            const int arr = e >> 9, ff = (e >> 4) & 31, ii = e & 15;
            const int f = f0 + ff;
            float val = 0.f;
            if (f < NF) {
                if (arr == 0) {
                    int Iu = TI + 1 + ii; if (Iu > SEQ - 1) Iu = SEQ - 1;
                    val = a1[((size_t)f << 9) + Iu] * sfac[f];
                } else {
                    int Ju = TJ + 1 + ii; if (Ju > SEQ - 1) Ju = SEQ - 1;
                    val = a1[((size_t)f << 9) + Ju];
                }
            }
            if (arr == 0) u_s[ff][ii] = val; else v_s[ff][ii] = val;
        }
        __syncthreads();
        #pragma unroll
        for (int ff = 0; ff < 32; ++ff)
            acc += u_s[ff][ty] * v_s[ff][tx];
        __syncthreads();
    }

    const int i = TI + ty, j = TJ + tx;
    if (i < CROP && j < CROP) {
        const int I = i + 1, J = j + 1;
        const float mi = (tokens[I] != EOSI) ? 1.f : 0.f;
        const float mj = (tokens[J] != EOSI) ? 1.f : 0.f;
        const float first = mi * mj * (WA[((size_t)I << 9) + J] + WA[((size_t)J << 9) + I]);
        const float logit = first - acc + bias[0];
        out[(size_t)i * CROP + j] = 1.f / (1.f + expf(-logit));
    }
}

extern "C" void kernel_launch(void* const* d_in, const int* in_sizes, int n_in,
                              void* d_out, int out_size, void* d_ws, size_t ws_size,
                              hipStream_t stream) {
    const int*   tokens = (const int*)d_in[0];
    const float* A      = (const float*)d_in[1];
    const float* weight = (const float*)d_in[2];
    const float* bias   = (const float*)d_in[3];
    float* out = (float*)d_out;

    // workspace (floats), all write-once, no zeroing:
    // WApart[33*512*512] | colpart[32*660*512] | WA[512*512] | rowsum[660*512] | a1[660*512] | sfac[660]
    float* WApart  = (float*)d_ws;
    float* colpart = WApart + (size_t)NG * SEQ * SEQ;
    float* WA      = colpart + (size_t)NT_ * NF * SEQ;
    float* rowsum  = WA + (size_t)SEQ * SEQ;
    float* a1      = rowsum + (size_t)NF * SEQ;
    float* sfac    = a1 + (size_t)NF * SEQ;

    dim3 g1(NT_, NG);   // 32 x 33
    pass1_kernel<<<g1, 256, 0, stream>>>(A, tokens, weight, WApart, rowsum, colpart);

    kernel2<<<128 + NF, 512, 0, stream>>>(WApart, WA, rowsum, colpart, tokens, weight, a1, sfac);

    dim3 g3(32, 32);
    pass3_kernel<<<g3, 256, 0, stream>>>(WA, a1, sfac, tokens, bias, out);
}